// Round 3
// baseline (214.370 us; speedup 1.0000x reference)
//
#include <hip/hip_runtime.h>
#include <hip/hip_bf16.h>

// out[i] = sum_{j!=i} relu(Wd_i@x_j + (Ws_i-Wd_i)@x_i + b_i) * x_j + x_i, 3 steps.
// MFMA 16x16x32 bf16, 3-way split (hi/mid/lo) of W and x -> fp32-equivalent.
// x lives in LDS ONLY as its 3 bf16 splits (value := h+m+l). Gating multiplier
// and the residual are reconstructed from the splits (diag branch adds xg).
// awd resident (48 VGPR); awsd recomputed transiently per step from global we.
// Final step: msg registers stored straight to global (no last LDS round-trip).

#define NN 8
#define NSTEPS 3
#define BB 4
#define CC 32
#define HWSZ 9216
#define PX 16
#define CPS 40   // bf16 row stride: 80 B, 16B-aligned, 2-way-conflict max

typedef __bf16 bf16x8 __attribute__((ext_vector_type(8)));
typedef __bf16 bf16x4 __attribute__((ext_vector_type(4)));
typedef __bf16 bf16x2 __attribute__((ext_vector_type(2)));
typedef float  f32x4  __attribute__((ext_vector_type(4)));
typedef float  f32x2  __attribute__((ext_vector_type(2)));

#define MFMA(A, B, C) __builtin_amdgcn_mfma_f32_16x16x32_bf16((A), (B), (C), 0, 0, 0)

__device__ __forceinline__ void split3(float v, __bf16& h, __bf16& m, __bf16& l) {
    h = (__bf16)v;
    float r1 = v - (float)h;
    m = (__bf16)r1;
    l = (__bf16)(r1 - (float)m);
}

__global__ __launch_bounds__(256, 3)
void gcn3_mfma2(const float* __restrict__ nodes,
                const float* __restrict__ we,
                const float* __restrict__ be,
                float* __restrict__ out) {
    __shared__ __bf16 xs[3][NN][PX][CPS];   // 30720 B

    const int tid  = threadIdx.x;
    const int wid  = tid >> 6;
    const int lane = tid & 63;
    const int col  = lane & 15;    // pixel (B-frag n, C col)
    const int quad = lane >> 4;    // 0..3

    // ---- resident A-frags: Wd only, 3-way split. A[m=col][k=quad*8+t] ----
    bf16x8 awd[2][2][3];   // [rec][tile][split]  = 48 VGPRs
    #pragma unroll
    for (int r = 0; r < 2; ++r) {
        const int ir = wid + 4 * r;
        #pragma unroll
        for (int t = 0; t < 2; ++t) {
            const float* wp = we + (size_t)((ir * CC + 16 * t + col) * (2 * CC)) + quad * 8;
            f32x4 w0 = *(const f32x4*)wp;
            f32x4 w1 = *(const f32x4*)(wp + 4);
            #pragma unroll
            for (int k = 0; k < 8; ++k) {
                float d = (k < 4) ? w0[k & 3] : w1[k & 3];
                __bf16 h, m, l;
                split3(d, h, m, l);
                awd[r][t][0][k] = h; awd[r][t][1][k] = m; awd[r][t][2][k] = l;
            }
        }
    }

    const int q0  = blockIdx.x * PX;
    const int b   = q0 / HWSZ;
    const int hw0 = q0 - b * HWSZ;

    // ---- stage: thread handles 2 channels x 2 pixels -> packed bf16x2 writes ----
    #pragma unroll
    for (int kk = 0; kk < 4; ++kk) {
        int idx = tid + kk * 256;            // 1024 units = 8n * 16c2 * 8p2
        int p2 = (idx & 7) * 2;
        int c2 = ((idx >> 3) & 15) * 2;
        int n  = idx >> 7;
        const float* gp = nodes + (size_t)((n * BB + b) * CC + c2) * HWSZ + hw0 + p2;
        f32x2 v0 = *(const f32x2*)gp;            // channel c2, pixels p2,p2+1
        f32x2 v1 = *(const f32x2*)(gp + HWSZ);   // channel c2+1
        #pragma unroll
        for (int e = 0; e < 2; ++e) {
            __bf16 h0, m0, l0, h1, m1, l1;
            split3(v0[e], h0, m0, l0);
            split3(v1[e], h1, m1, l1);
            *(bf16x2*)&xs[0][n][p2 + e][c2] = bf16x2{h0, h1};
            *(bf16x2*)&xs[1][n][p2 + e][c2] = bf16x2{m0, m1};
            *(bf16x2*)&xs[2][n][p2 + e][c2] = bf16x2{l0, l1};
        }
    }
    __syncthreads();

    f32x4 msg[2][2];

    #pragma unroll 1
    for (int step = 0; step < NSTEPS; ++step) {
        asm volatile("" ::: "memory");   // force per-step reload of we/be (keeps awsd transient)

        // ---- Q = (Ws-Wd)_i @ x_i + b : transient wsd split per (r,t) ----
        f32x4 qf[2][2];
        #pragma unroll
        for (int r = 0; r < 2; ++r) {
            const int ir = wid + 4 * r;
            bf16x8 bq0 = *(const bf16x8*)&xs[0][ir][col][quad * 8];
            bf16x8 bq1 = *(const bf16x8*)&xs[1][ir][col][quad * 8];
            bf16x8 bq2 = *(const bf16x8*)&xs[2][ir][col][quad * 8];
            #pragma unroll
            for (int t = 0; t < 2; ++t) {
                const float* wp = we + (size_t)((ir * CC + 16 * t + col) * (2 * CC)) + quad * 8;
                f32x4 d0 = *(const f32x4*)wp;
                f32x4 d1 = *(const f32x4*)(wp + 4);
                f32x4 s0 = *(const f32x4*)(wp + CC);
                f32x4 s1 = *(const f32x4*)(wp + CC + 4);
                bf16x8 ah, am, al;
                #pragma unroll
                for (int k = 0; k < 8; ++k) {
                    float sv = ((k < 4) ? s0[k & 3] : s1[k & 3]) - ((k < 4) ? d0[k & 3] : d1[k & 3]);
                    __bf16 h, m, l;
                    split3(sv, h, m, l);
                    ah[k] = h; am[k] = m; al[k] = l;
                }
                f32x4 acc = *(const f32x4*)(be + ir * CC + 16 * t + quad * 4);
                acc = MFMA(ah, bq0, acc);
                acc = MFMA(ah, bq1, acc);
                acc = MFMA(am, bq0, acc);
                acc = MFMA(ah, bq2, acc);
                acc = MFMA(al, bq0, acc);
                acc = MFMA(am, bq1, acc);
                qf[r][t] = acc;
            }
        }

        #pragma unroll
        for (int r = 0; r < 2; ++r)
            #pragma unroll
            for (int t = 0; t < 2; ++t)
                msg[r][t] = f32x4{0.f, 0.f, 0.f, 0.f};

        // ---- sender loop ----
        #pragma unroll
        for (int j = 0; j < NN; ++j) {
            bf16x8 bj0 = *(const bf16x8*)&xs[0][j][col][quad * 8];
            bf16x8 bj1 = *(const bf16x8*)&xs[1][j][col][quad * 8];
            bf16x8 bj2 = *(const bf16x8*)&xs[2][j][col][quad * 8];
            // gating multiplier x_j at C-layout rows 16t+4*quad+k, pixel col
            f32x4 xg[2];
            #pragma unroll
            for (int t = 0; t < 2; ++t) {
                bf16x4 h4 = *(const bf16x4*)&xs[0][j][col][16 * t + quad * 4];
                bf16x4 m4 = *(const bf16x4*)&xs[1][j][col][16 * t + quad * 4];
                bf16x4 l4 = *(const bf16x4*)&xs[2][j][col][16 * t + quad * 4];
                #pragma unroll
                for (int k = 0; k < 4; ++k)
                    xg[t][k] = (float)h4[k] + (float)m4[k] + (float)l4[k];
            }
            #pragma unroll
            for (int r = 0; r < 2; ++r) {
                const int ir = wid + 4 * r;
                if (j == ir) {   // wave-uniform branch: residual term
                    #pragma unroll
                    for (int t = 0; t < 2; ++t)
                        #pragma unroll
                        for (int k = 0; k < 4; ++k)
                            msg[r][t][k] += xg[t][k];
                } else {
                    #pragma unroll
                    for (int t = 0; t < 2; ++t) {
                        f32x4 e = qf[r][t];
                        e = MFMA(awd[r][t][0], bj0, e);
                        e = MFMA(awd[r][t][0], bj1, e);
                        e = MFMA(awd[r][t][1], bj0, e);
                        e = MFMA(awd[r][t][0], bj2, e);
                        e = MFMA(awd[r][t][2], bj0, e);
                        e = MFMA(awd[r][t][1], bj1, e);
                        #pragma unroll
                        for (int k = 0; k < 4; ++k)
                            msg[r][t][k] = fmaf(fmaxf(e[k], 0.f), xg[t][k], msg[r][t][k]);
                    }
                }
            }
        }

        if (step < NSTEPS - 1) {
            __syncthreads();   // all reads of old x done
            #pragma unroll
            for (int r = 0; r < 2; ++r) {
                const int ir = wid + 4 * r;
                #pragma unroll
                for (int t = 0; t < 2; ++t) {
                    bf16x4 h4, m4, l4;
                    #pragma unroll
                    for (int k = 0; k < 4; ++k) {
                        __bf16 h, m, l;
                        split3(msg[r][t][k], h, m, l);
                        h4[k] = h; m4[k] = m; l4[k] = l;
                    }
                    *(bf16x4*)&xs[0][ir][col][16 * t + quad * 4] = h4;
                    *(bf16x4*)&xs[1][ir][col][16 * t + quad * 4] = m4;
                    *(bf16x4*)&xs[2][ir][col][16 * t + quad * 4] = l4;
                }
            }
            __syncthreads();   // new x visible
        }
    }

    // ---- final: store msg straight to global (rows of 16 px = 64B coalesced) ----
    #pragma unroll
    for (int r = 0; r < 2; ++r) {
        const int ir = wid + 4 * r;
        #pragma unroll
        for (int t = 0; t < 2; ++t) {
            float* op = out + (size_t)((ir * BB + b) * CC + 16 * t + quad * 4) * HWSZ + hw0 + col;
            #pragma unroll
            for (int k = 0; k < 4; ++k)
                op[(size_t)k * HWSZ] = msg[r][t][k];
        }
    }
}

extern "C" void kernel_launch(void* const* d_in, const int* in_sizes, int n_in,
                              void* d_out, int out_size, void* d_ws, size_t ws_size,
                              hipStream_t stream) {
    const float* nodes  = (const float*)d_in[0];
    const float* W_edge = (const float*)d_in[1];
    const float* b_edge = (const float*)d_in[2];
    float* outp = (float*)d_out;

    dim3 grid((BB * HWSZ) / PX);   // 2304
    dim3 block(256);
    gcn3_mfma2<<<grid, block, 0, stream>>>(nodes, W_edge, b_edge, outp);
}